// Round 12
// baseline (67.315 us; speedup 1.0000x reference)
//
#include <hip/hip_runtime.h>
#include <hip/hip_bf16.h>

// PWL monotone interpolation, N=2097152, C=16, B=32.
// One CHANNEL per thread (c = tid&15, dword grid-stride, coalesced).
// Search levels 1-4 in 15 per-channel VGPRs -- PINNED with asm volatile
// ("+v") so the compiler cannot rematerialize them as in-loop global loads
// (R9/R11 failure: VGPR_Count=20 proved remat). Level 5 = one ROT-permuted
// LDS b32; (a,b) fused float2 = one ROT-permuted LDS b64. 2 LDS instrs/elem.

#define C_CH 16
#define B_KN 32

#define ROT(k) ((((k) << 2) | ((k) >> 3)) & 31)

// ws float layout: [0..511]=xs(c*32+k), [512..1023]=a(c*32+s), [1024..1535]=b

// ---------------- setup: sort knots, cumsum ys, per-segment a,b ----------------
__global__ __launch_bounds__(512) void pwl_setup_kernel(
    const float* __restrict__ xp, const float* __restrict__ y0,
    const float* __restrict__ dy, float* __restrict__ ws) {
    __shared__ float s_x[C_CH][B_KN];
    __shared__ float s_xs[C_CH][B_KN];
    __shared__ float s_ys[C_CH][B_KN];
    int t = threadIdx.x;
    int c = t >> 5;
    int k = t & 31;
    float v = xp[c * B_KN + k];
    s_x[c][k] = v;
    __syncthreads();
    int rank = 0;
#pragma unroll
    for (int j = 0; j < B_KN; ++j) {
        float u = s_x[c][j];
        rank += (u < v || (u == v && j < k)) ? 1 : 0;
    }
    s_xs[c][rank] = v;
    float acc = y0[c];
    for (int j = 0; j < k; ++j) acc += fabsf(dy[c * (B_KN - 1) + j]);
    s_ys[c][k] = acc;
    __syncthreads();
    ws[c * B_KN + k] = s_xs[c][k];
    if (k < B_KN - 1) {
        float x0 = s_xs[c][k], x1 = s_xs[c][k + 1];
        float ya = s_ys[c][k], yb = s_ys[c][k + 1];
        float a = (yb - ya) / (x1 - x0);
        float b = ya - a * x0;
        ws[512 + c * B_KN + k]  = a;
        ws[1024 + c * B_KN + k] = b;
    } else {
        ws[512 + c * B_KN + k]  = 0.0f;
        ws[1024 + c * B_KN + k] = 0.0f;
    }
}

// ---------------- main: one channel per thread, pinned register tree ----------------
__global__ __launch_bounds__(256) void pwl_main_kernel(
    const float* __restrict__ x, float* __restrict__ out,
    const float* __restrict__ ws, int n) {
    __shared__ float  s_xs[C_CH][B_KN + 1];   // entry k at [c][ROT(k)]
    __shared__ float2 s_ab[C_CH][B_KN + 1];   // (a,b) at [c][ROT(s)]
    int t = threadIdx.x;
    for (int p = t; p < C_CH * B_KN; p += 256) {
        int c = p >> 5, k = p & 31;
        int rk = ROT(k);
        s_xs[c][rk] = ws[p];
        s_ab[c][rk] = make_float2(ws[512 + p], ws[1024 + p]);
    }
    int tid = blockIdx.x * 256 + t;
    int c = tid & 15;                      // fixed channel for this thread
    const float* xsg = ws + c * B_KN;
    float v15_ = xsg[15];
    float v7_  = xsg[7],  v23_ = xsg[23];
    float v3_  = xsg[3],  v11_ = xsg[11], v19_ = xsg[19], v27_ = xsg[27];
    float v1_  = xsg[1],  v5_  = xsg[5],  v9_  = xsg[9],  v13_ = xsg[13];
    float v17_ = xsg[17], v21_ = xsg[21], v25_ = xsg[25], v29_ = xsg[29];
    __syncthreads();

    int T = gridDim.x * 256;
    for (int f = tid; f < n; f += 4 * T) {
        // pin the tree in VGPRs: "+v" marks them modified -> remat illegal
        asm volatile("" : "+v"(v15_), "+v"(v7_), "+v"(v23_), "+v"(v3_),
                          "+v"(v11_), "+v"(v19_), "+v"(v27_), "+v"(v1_),
                          "+v"(v5_), "+v"(v9_), "+v"(v13_), "+v"(v17_),
                          "+v"(v21_), "+v"(v25_), "+v"(v29_));
        int f1 = f + T, f2 = f + 2 * T, f3 = f + 3 * T;
        float x0 = x[f];
        float x1 = (f1 < n) ? x[f1] : x0;
        float x2 = (f2 < n) ? x[f2] : x0;
        float x3 = (f3 < n) ? x[f3] : x0;
        float xv[4] = {x0, x1, x2, x3};
        float rr[4];
#pragma unroll
        for (int u = 0; u < 4; ++u) {
            float xq = xv[u];
            bool b5 = (v15_ < xq);
            int pos = b5 ? 16 : 0;
            float t4 = b5 ? v23_ : v7_;
            bool b4 = (t4 < xq);
            pos += b4 ? 8 : 0;
            float ta = b4 ? v11_ : v3_;
            float tb = b4 ? v27_ : v19_;
            float t3 = b5 ? tb : ta;
            bool b3 = (t3 < xq);
            pos += b3 ? 4 : 0;
            float u0 = b3 ? v5_  : v1_;
            float u1 = b3 ? v13_ : v9_;
            float uu = b4 ? u1 : u0;
            float w0 = b3 ? v21_ : v17_;
            float w1 = b3 ? v29_ : v25_;
            float ww = b4 ? w1 : w0;
            float z  = b5 ? ww : uu;
            bool b2 = (z < xq);
            pos += b2 ? 2 : 0;
            pos += (s_xs[c][ROT(pos)] < xq) ? 1 : 0;   // level s=1 (even pos)
            int seg = (pos > 1 ? pos : 1) - 1;          // clip(searchsorted,1,31)-1
            seg = seg > 30 ? 30 : seg;
            float2 ab = s_ab[c][ROT(seg)];
            rr[u] = fmaf(ab.x, xq, ab.y);
        }
        out[f] = rr[0];
        if (f1 < n) out[f1] = rr[1];
        if (f2 < n) out[f2] = rr[2];
        if (f3 < n) out[f3] = rr[3];
    }
}

extern "C" void kernel_launch(void* const* d_in, const int* in_sizes, int n_in,
                              void* d_out, int out_size, void* d_ws, size_t ws_size,
                              hipStream_t stream) {
    const float* x  = (const float*)d_in[0];
    const float* xp = (const float*)d_in[1];
    const float* y0 = (const float*)d_in[2];
    const float* dy = (const float*)d_in[3];
    float* out = (float*)d_out;
    float* ws  = (float*)d_ws;

    pwl_setup_kernel<<<1, 512, 0, stream>>>(xp, y0, dy, ws);

    int n = in_sizes[0];       // 33554432 flat elements
    pwl_main_kernel<<<2048, 256, 0, stream>>>(x, out, ws, n);
}

// Round 13
// 52.795 us; speedup vs baseline: 1.2750x; 1.2750x over previous
//
#include <hip/hip_runtime.h>
#include <hip/hip_bf16.h>

// PWL monotone interpolation, N=2097152, C=16, B=32.
// R8 structure exactly (ROT-permuted LDS tables, stride 33, full 5-level LDS
// binary search, simple grid-stride float4 loop), ONE change: the two a/b
// gathers are fused into a single ds_read_b64 of an interleaved float2
// (ROT-permuted), cutting LDS instrs/elem 7 -> 6.

#define C_CH 16
#define B_KN 32

#define ROT(k) ((((k) << 2) | ((k) >> 3)) & 31)

// ws float layout: [0..511]=xs(c*32+k), [512..1023]=a(c*32+s), [1024..1535]=b

// ---------------- setup: sort knots, cumsum ys, per-segment a,b ----------------
__global__ __launch_bounds__(512) void pwl_setup_kernel(
    const float* __restrict__ xp, const float* __restrict__ y0,
    const float* __restrict__ dy, float* __restrict__ ws) {
    __shared__ float s_x[C_CH][B_KN];
    __shared__ float s_xs[C_CH][B_KN];
    __shared__ float s_ys[C_CH][B_KN];
    int t = threadIdx.x;
    int c = t >> 5;
    int k = t & 31;
    float v = xp[c * B_KN + k];
    s_x[c][k] = v;
    __syncthreads();
    int rank = 0;
#pragma unroll
    for (int j = 0; j < B_KN; ++j) {
        float u = s_x[c][j];
        rank += (u < v || (u == v && j < k)) ? 1 : 0;
    }
    s_xs[c][rank] = v;
    float acc = y0[c];
    for (int j = 0; j < k; ++j) acc += fabsf(dy[c * (B_KN - 1) + j]);
    s_ys[c][k] = acc;
    __syncthreads();
    ws[c * B_KN + k] = s_xs[c][k];
    if (k < B_KN - 1) {
        float x0 = s_xs[c][k], x1 = s_xs[c][k + 1];
        float ya = s_ys[c][k], yb = s_ys[c][k + 1];
        float a = (yb - ya) / (x1 - x0);
        float b = ya - a * x0;
        ws[512 + c * B_KN + k]  = a;
        ws[1024 + c * B_KN + k] = b;
    } else {
        ws[512 + c * B_KN + k]  = 0.0f;
        ws[1024 + c * B_KN + k] = 0.0f;
    }
}

// ---------------- main: R8 loop, ROT-permuted LDS, fused (a,b) b64 ----------------
__global__ __launch_bounds__(256) void pwl_main_kernel(
    const float4* __restrict__ x, float4* __restrict__ out,
    const float* __restrict__ ws, int n4) {
    __shared__ float  s_xs[C_CH][B_KN + 1];   // entry k stored at [c][ROT(k)]
    __shared__ float2 s_ab[C_CH][B_KN + 1];   // (a,b) stored at [c][ROT(s)]
    for (int i = threadIdx.x; i < C_CH * B_KN; i += 256) {
        int c = i >> 5, k = i & 31;
        int rk = ROT(k);
        s_xs[c][rk] = ws[i];
        s_ab[c][rk] = make_float2(ws[512 + i], ws[1024 + i]);
    }
    __syncthreads();

    int tid = blockIdx.x * 256 + threadIdx.x;
    int stride = gridDim.x * 256;
    int c0 = (threadIdx.x & 3) << 2;   // i&3 constant per thread (stride % 4 == 0)
    for (int i = tid; i < n4; i += stride) {
        float4 v = x[i];
        float xv[4] = {v.x, v.y, v.z, v.w};
        float r[4];
#pragma unroll
        for (int j = 0; j < 4; ++j) {
            int c = c0 + j;
            float xq = xv[j];
            const float* xs = s_xs[c];
            // branchless lower_bound: pos = min(#{xs[i] < xq}, 31)
            int pos = 0;
#pragma unroll
            for (int s = 16; s >= 1; s >>= 1) {
                int idx = pos + s - 1;
                pos += (xs[ROT(idx)] < xq) ? s : 0;
            }
            int seg = (pos > 1 ? pos : 1) - 1;  // clip(searchsorted,1,31)-1
            seg = seg > 30 ? 30 : seg;
            float2 ab = s_ab[c][ROT(seg)];
            r[j] = fmaf(ab.x, xq, ab.y);
        }
        out[i] = make_float4(r[0], r[1], r[2], r[3]);
    }
}

extern "C" void kernel_launch(void* const* d_in, const int* in_sizes, int n_in,
                              void* d_out, int out_size, void* d_ws, size_t ws_size,
                              hipStream_t stream) {
    const float* x  = (const float*)d_in[0];
    const float* xp = (const float*)d_in[1];
    const float* y0 = (const float*)d_in[2];
    const float* dy = (const float*)d_in[3];
    float* out = (float*)d_out;
    float* ws  = (float*)d_ws;

    pwl_setup_kernel<<<1, 512, 0, stream>>>(xp, y0, dy, ws);

    int n4 = in_sizes[0] / 4;  // 8388608
    int blocks = (n4 + 255) / 256;
    if (blocks > 2048) blocks = 2048;
    pwl_main_kernel<<<blocks, 256, 0, stream>>>((const float4*)x, (float4*)out, ws, n4);
}